// Round 4
// baseline (910.057 us; speedup 1.0000x reference)
//
#include <hip/hip_runtime.h>

#define NPTS 4096
#define CH 64
#define BATCH 8
#define KNN 20
#define NEG_SLOPE 0.2f
#define EPSV 1e-5f
#define NEG_INF (-3.4e38f)
#define MCHUNK 2048          // columns scanned per block (2 chunks)
#define MTILES (MCHUNK/128)  // 16 tiles of 128 cols

// ---------------- K0: xx[b,n] = sum_c x[b,c,n]^2 ----------------
__global__ void k_xx(const float* __restrict__ x, float* __restrict__ xx) {
  int t = blockIdx.x * 256 + threadIdx.x;
  int b = t >> 12, n = t & (NPTS - 1);
  const float* xp = x + ((size_t)b * CH * NPTS) + n;
  float s = 0.f;
#pragma unroll
  for (int c = 0; c < CH; ++c) { float v = xp[(size_t)c * NPTS]; s = fmaf(v, v, s); }
  xx[t] = s;
}

// ---------------- K2: P'[t,o], Q'[t,o] ----------------
__global__ void k_pq(const float* __restrict__ x, const float* __restrict__ W,
                     const float* __restrict__ gamma, const float* __restrict__ beta,
                     const float* __restrict__ rmean, const float* __restrict__ rvar,
                     float* __restrict__ P, float* __restrict__ Q) {
  __shared__ float Ws1[CH * CH];
  __shared__ float Wsd[CH * CH];
  int tid = threadIdx.x;
  for (int i = tid; i < CH * CH; i += 256) {
    int o = i & 63, c = i >> 6;
    float s = gamma[o] * rsqrtf(rvar[o] + EPSV);
    float w1 = W[o * 128 + c], w2 = W[o * 128 + 64 + c];
    Ws1[c * 64 + o] = w1 * s;
    Wsd[c * 64 + o] = (w2 - w1) * s;
  }
  __syncthreads();
  int o = tid & 63, ng = tid >> 6;
  float s = gamma[o] * rsqrtf(rvar[o] + EPSV);
  float shift = beta[o] - rmean[o] * s;
  int base = blockIdx.x * 16;
  for (int rp = 0; rp < 4; ++rp) {
    int t = base + rp * 4 + ng;
    int b = t >> 12, n = t & (NPTS - 1);
    const float* xp = x + ((size_t)b * CH * NPTS) + n;
    float accp = 0.f, accq = 0.f;
#pragma unroll 8
    for (int c = 0; c < CH; ++c) {
      float xv = xp[(size_t)c * NPTS];
      accp = fmaf(xv, Ws1[c * 64 + o], accp);
      accq = fmaf(xv, Wsd[c * 64 + o], accq);
    }
    P[(size_t)t * 64 + o] = accp;
    Q[(size_t)t * 64 + o] = accq + shift;
  }
}

// ---------------- K1: distance-GEMM (8x8 regtile) + wave top-20, m-chunked ----
// Block: 256 thr. Tile 128 rows x 128 cols, thread-tile 8x8 (4+4 split both dims
// so every LDS instr covers all 32 banks). LDS: As[c][128] 32KB + Bs[c][128] 32KB
// = 64KB; Ds (64 rows x 128) overlays Bs, selection in 2 half-row passes.
// Each block scans MCHUNK cols; per-chunk top-20 (val,idx) -> ws, merged later.
__launch_bounds__(256, 2)
__global__ void k_knn(const float* __restrict__ x, const float* __restrict__ xx,
                      float* __restrict__ pv, int* __restrict__ pi) {
  __shared__ float S[16384];     // 64 KB
  float* As = S;                 // [c*128 + row]
  float* Bs = S + 8192;          // [c*128 + col]  (dead after GEMM of a tile)
  float* Ds = S + 8192;          // [rlocal*128 + col] overlay
  int tid = threadIdx.x;
  int lane = tid & 63, w = tid >> 6;
  int nb = blockIdx.x;           // 0..31
  int mc = blockIdx.y;           // 0..1 column chunk
  int b  = blockIdx.z;           // 0..7
  int n0 = nb * 128;
  int mbase = mc * MCHUNK;
  const float* xb = x + (size_t)b * CH * NPTS;
  const float* xxb = xx + b * NPTS;

  // stage A-tile [c][128 rows] once
#pragma unroll
  for (int k = 0; k < 8; ++k) {
    int chunk = tid + 256 * k;                   // 0..2047
    int c = chunk >> 5, rn = (chunk & 31) << 2;
    float4 v = *(const float4*)(xb + (size_t)c * NPTS + n0 + rn);
    *(float4*)(As + c * 128 + rn) = v;
  }

  int rg = tid >> 4, cg = tid & 15;              // rows {4rg,64+4rg}, cols {4cg,64+4cg}

  float xnr[2][4];
#pragma unroll
  for (int ic = 0; ic < 2; ++ic)
#pragma unroll
    for (int i = 0; i < 4; ++i) xnr[ic][i] = xxb[n0 + 64 * ic + 4 * rg + i];

  // wave w owns rows {16w+r} (ic=0) and {64+16w+r} (ic=1), r=0..15
  float val[2][16]; int idx[2][16];
#pragma unroll
  for (int ic = 0; ic < 2; ++ic)
#pragma unroll
    for (int r = 0; r < 16; ++r) { val[ic][r] = NEG_INF; idx[ic][r] = 0; }

  for (int mt = 0; mt < MTILES; ++mt) {
    int m0 = mbase + mt * 128;
    __syncthreads();                             // prev sel reads / A-stage done
#pragma unroll
    for (int k = 0; k < 8; ++k) {
      int chunk = tid + 256 * k;
      int c = chunk >> 5, cm = (chunk & 31) << 2;
      float4 v = *(const float4*)(xb + (size_t)c * NPTS + m0 + cm);
      *(float4*)(Bs + c * 128 + cm) = v;
    }
    __syncthreads();

    float acc[2][4][2][4];
#pragma unroll
    for (int ic = 0; ic < 2; ++ic)
#pragma unroll
      for (int i = 0; i < 4; ++i)
#pragma unroll
        for (int jc = 0; jc < 2; ++jc)
#pragma unroll
          for (int j = 0; j < 4; ++j) acc[ic][i][jc][j] = 0.f;

#pragma unroll 2
    for (int c = 0; c < CH; ++c) {
      float4 a0 = *(const float4*)(As + c * 128 + 4 * rg);
      float4 a1 = *(const float4*)(As + c * 128 + 64 + 4 * rg);
      float4 b0 = *(const float4*)(Bs + c * 128 + 4 * cg);
      float4 b1 = *(const float4*)(Bs + c * 128 + 64 + 4 * cg);
      float av[2][4] = {{a0.x, a0.y, a0.z, a0.w}, {a1.x, a1.y, a1.z, a1.w}};
      float bv[2][4] = {{b0.x, b0.y, b0.z, b0.w}, {b1.x, b1.y, b1.z, b1.w}};
#pragma unroll
      for (int ic = 0; ic < 2; ++ic)
#pragma unroll
        for (int i = 0; i < 4; ++i)
#pragma unroll
          for (int jc = 0; jc < 2; ++jc)
#pragma unroll
            for (int j = 0; j < 4; ++j)
              acc[ic][i][jc][j] = fmaf(av[ic][i], bv[jc][j], acc[ic][i][jc][j]);
    }

    float xmv[2][4];
#pragma unroll
    for (int jc = 0; jc < 2; ++jc)
#pragma unroll
      for (int j = 0; j < 4; ++j) xmv[jc][j] = xxb[m0 + 64 * jc + 4 * cg + j];

#pragma unroll
    for (int ic = 0; ic < 2; ++ic) {
      __syncthreads();                           // Bs reads (ic=0) / sel pass0 (ic=1) done
      // write distances for row-cluster ic (64 rows) into Ds
#pragma unroll
      for (int i = 0; i < 4; ++i) {
        int Rl = 4 * rg + i;                     // 0..63
#pragma unroll
        for (int jc = 0; jc < 2; ++jc) {
          float4 d;
          d.x = (2.f * acc[ic][i][jc][0] - xnr[ic][i]) - xmv[jc][0];
          d.y = (2.f * acc[ic][i][jc][1] - xnr[ic][i]) - xmv[jc][1];
          d.z = (2.f * acc[ic][i][jc][2] - xnr[ic][i]) - xmv[jc][2];
          d.w = (2.f * acc[ic][i][jc][3] - xnr[ic][i]) - xmv[jc][3];
          *(float4*)(Ds + Rl * 128 + 64 * jc + 4 * cg) = d;
        }
      }
      __syncthreads();
      // selection: wave w scans its 16 rows of this pass
#pragma unroll
      for (int r = 0; r < 16; ++r) {
        int Rl = 16 * w + r;
        const float* drow = Ds + Rl * 128;
#pragma unroll
        for (int g = 0; g < 2; ++g) {
          float d = drow[64 * g + lane];
          float th = __shfl(val[ic][r], KNN - 1);
          unsigned long long hit = __ballot(d > th);
          int mg = m0 + 64 * g;
          while (hit) {
            int j = __builtin_ctzll(hit);
            hit &= hit - 1;
            float cv = __shfl(d, j);
            int cm = mg + j;
            unsigned long long km = __ballot(val[ic][r] >= cv);
            int cnt = __popcll(km);
            float sv = __shfl_up(val[ic][r], 1);
            int si = __shfl_up(idx[ic][r], 1);
            if (lane >= cnt) {
              val[ic][r] = (lane == cnt) ? cv : sv;
              idx[ic][r] = (lane == cnt) ? cm : si;
            }
          }
        }
      }
    }
  }

  // emit per-chunk top-20 (val,idx)
#pragma unroll
  for (int ic = 0; ic < 2; ++ic)
#pragma unroll
    for (int r = 0; r < 16; ++r) {
      int n = n0 + 64 * ic + 16 * w + r;
      size_t row = (size_t)mc * (BATCH * NPTS) + b * NPTS + n;
      if (lane < KNN) {
        pv[row * KNN + lane] = val[ic][r];
        pi[row * KNN + lane] = idx[ic][r];
      }
    }
}

// ---------------- K1b: merge two sorted 20-lists per row ----------------
__global__ void k_merge(const float* __restrict__ pv, const int* __restrict__ pi,
                        int* __restrict__ idxout) {
  int row = blockIdx.x * 256 + threadIdx.x;      // 0..32767
  const float* v0 = pv + (size_t)row * KNN;
  const int*   i0 = pi + (size_t)row * KNN;
  const float* v1 = pv + ((size_t)BATCH * NPTS + row) * KNN;
  const int*   i1 = pi + ((size_t)BATCH * NPTS + row) * KNN;
  int* op = idxout + (size_t)row * KNN;
  int p0 = 0, p1 = 0;
#pragma unroll
  for (int k = 0; k < KNN; ++k) {
    float f0 = v0[p0], f1 = v1[p1];
    // chunk0 indices are always smaller -> ties go to chunk0 (lax.top_k stable)
    if (f0 >= f1) { op[k] = i0[p0++]; } else { op[k] = i1[p1++]; }
  }
}

// ---------------- K3: gather + max + leaky, transpose to (B,O,N) ----------------
__global__ void k_out(const float* __restrict__ P, const float* __restrict__ Q,
                      const int* __restrict__ idx, float* __restrict__ out) {
  __shared__ float T[64 * 65];
  int tid = threadIdx.x;
  int nb = blockIdx.x, b = blockIdx.y;
  int n0 = nb * 64;
  int o = tid & 63, ng = tid >> 6;
  const float* Pb = P + (size_t)b * NPTS * 64;
  for (int p = 0; p < 16; ++p) {
    int nl = p * 4 + ng;
    int n = n0 + nl;
    const int* ip = idx + (size_t)(b * NPTS + n) * KNN;
    float mx = NEG_INF;
#pragma unroll
    for (int k = 0; k < KNN; ++k) {
      int id = ip[k];
      float v = Pb[(size_t)id * 64 + o];
      mx = fmaxf(mx, v);
    }
    float z = mx + Q[(size_t)(b * NPTS + n) * 64 + o];
    z = (z >= 0.f) ? z : NEG_SLOPE * z;
    T[o * 65 + nl] = z;
  }
  __syncthreads();
  float* ob = out + (size_t)b * 64 * NPTS + n0;
  int nl = tid & 63;
  for (int w = 0; w < 16; ++w) {
    int oo = w * 4 + ng;
    ob[(size_t)oo * NPTS + nl] = T[oo * 65 + nl];
  }
}

extern "C" void kernel_launch(void* const* d_in, const int* in_sizes, int n_in,
                              void* d_out, int out_size, void* d_ws, size_t ws_size,
                              hipStream_t stream) {
  const float* x     = (const float*)d_in[0];
  const float* W     = (const float*)d_in[1];
  const float* gamma = (const float*)d_in[2];
  const float* beta  = (const float*)d_in[3];
  const float* rmean = (const float*)d_in[4];
  const float* rvar  = (const float*)d_in[5];
  float* out = (float*)d_out;

  // ws layout (floats): xx 32768 | idx 655360 (int) | region:
  //   phase A: pv 1310720 f, pi 1310720 i   (k_knn -> k_merge)
  //   phase B: P 2097152 f,  Q 2097152 f    (k_pq  -> k_out)   [overlaps pv/pi]
  float* xx  = (float*)d_ws;
  int*   idx = (int*)(xx + 32768);
  float* reg = (float*)(idx + 655360);
  float* pv  = reg;
  int*   pi  = (int*)(reg + 1310720);
  float* P   = reg;
  float* Q   = reg + 2097152;

  k_xx<<<BATCH * NPTS / 256, 256, 0, stream>>>(x, xx);
  k_knn<<<dim3(NPTS / 128, 2, BATCH), 256, 0, stream>>>(x, xx, pv, pi);
  k_merge<<<BATCH * NPTS / 256, 256, 0, stream>>>(pv, pi, idx);
  k_pq<<<BATCH * NPTS / 16, 256, 0, stream>>>(x, W, gamma, beta, rmean, rvar, P, Q);
  k_out<<<dim3(NPTS / 64, BATCH), 256, 0, stream>>>(P, Q, idx, out);
}

// Round 5
// 908.044 us; speedup vs baseline: 1.0022x; 1.0022x over previous
//
#include <hip/hip_runtime.h>

#define NPTS 4096
#define CH 64
#define BATCH 8
#define KNN 20
#define NEG_SLOPE 0.2f
#define EPSV 1e-5f
#define NEG_INF (-3.4e38f)
#define MCHUNK 2048          // columns scanned per block
#define MTILES (MCHUNK/128)  // 16 tiles of 128 cols

// ---------------- K0: xx[b,n] = sum_c x[b,c,n]^2 ----------------
__global__ void k_xx(const float* __restrict__ x, float* __restrict__ xx) {
  int t = blockIdx.x * 256 + threadIdx.x;
  int b = t >> 12, n = t & (NPTS - 1);
  const float* xp = x + ((size_t)b * CH * NPTS) + n;
  float s = 0.f;
#pragma unroll
  for (int c = 0; c < CH; ++c) { float v = xp[(size_t)c * NPTS]; s = fmaf(v, v, s); }
  xx[t] = s;
}

// ---------------- K2: P'[t,o], Q'[t,o] ----------------
__global__ void k_pq(const float* __restrict__ x, const float* __restrict__ W,
                     const float* __restrict__ gamma, const float* __restrict__ beta,
                     const float* __restrict__ rmean, const float* __restrict__ rvar,
                     float* __restrict__ P, float* __restrict__ Q) {
  __shared__ float Ws1[CH * CH];
  __shared__ float Wsd[CH * CH];
  int tid = threadIdx.x;
  for (int i = tid; i < CH * CH; i += 256) {
    int o = i & 63, c = i >> 6;
    float s = gamma[o] * rsqrtf(rvar[o] + EPSV);
    float w1 = W[o * 128 + c], w2 = W[o * 128 + 64 + c];
    Ws1[c * 64 + o] = w1 * s;
    Wsd[c * 64 + o] = (w2 - w1) * s;
  }
  __syncthreads();
  int o = tid & 63, ng = tid >> 6;
  float s = gamma[o] * rsqrtf(rvar[o] + EPSV);
  float shift = beta[o] - rmean[o] * s;
  int base = blockIdx.x * 16;
  for (int rp = 0; rp < 4; ++rp) {
    int t = base + rp * 4 + ng;
    int b = t >> 12, n = t & (NPTS - 1);
    const float* xp = x + ((size_t)b * CH * NPTS) + n;
    float accp = 0.f, accq = 0.f;
#pragma unroll 8
    for (int c = 0; c < CH; ++c) {
      float xv = xp[(size_t)c * NPTS];
      accp = fmaf(xv, Ws1[c * 64 + o], accp);
      accq = fmaf(xv, Wsd[c * 64 + o], accq);
    }
    P[(size_t)t * 64 + o] = accp;
    Q[(size_t)t * 64 + o] = accq + shift;
  }
}

// ---------------- K1: distance-GEMM + wave top-20, 3 blocks/CU ----------------
// Block 256 thr. Tile 64 rows x 128 cols, thread-tile 4x8 (cols split 4+4).
// LDS: As[c][64] 16KB + (Bs[c][128] 32KB EXACT-overlaid by Ds[64][128] 32KB)
//      = 48KB -> 3 blocks/CU. Grid (32,2,8)=... (64 row-tiles? rows 4096/64=64)
//      grid (64 nb, 2 mc, 8 b) = 1024 blocks -> 3/CU resident (was 2).
// All LDS patterns are the R4-proven 0-conflict ones.
__launch_bounds__(256, 3)
__global__ void k_knn(const float* __restrict__ x, const float* __restrict__ xx,
                      float* __restrict__ pv, int* __restrict__ pi) {
  __shared__ float S[12288];     // 48 KB
  float* As = S;                 // [c*64 + row]
  float* Bs = S + 4096;          // [c*128 + col]
  float* Ds = S + 4096;          // [r*128 + col] overlay (exactly Bs-sized)
  int tid = threadIdx.x;
  int lane = tid & 63, w = tid >> 6;
  int nb = blockIdx.x;           // 0..63
  int mc = blockIdx.y;           // 0..1
  int b  = blockIdx.z;           // 0..7
  int n0 = nb * 64;
  int mbase = mc * MCHUNK;
  const float* xb = x + (size_t)b * CH * NPTS;
  const float* xxb = xx + b * NPTS;

  // stage A-tile [c][64 rows] once
#pragma unroll
  for (int k = 0; k < 4; ++k) {
    int chunk = tid + 256 * k;                   // 0..1023
    int c = chunk >> 4, rn = (chunk & 15) << 2;
    float4 v = *(const float4*)(xb + (size_t)c * NPTS + n0 + rn);
    *(float4*)(As + c * 64 + rn) = v;
  }

  int rg = tid >> 4, cg = tid & 15;              // rows 4rg..+3, cols {4cg,64+4cg}..+3

  float xnr[4];
#pragma unroll
  for (int i = 0; i < 4; ++i) xnr[i] = xxb[n0 + 4 * rg + i];

  // distributed top-20: lane l holds l-th best of row 16w+r
  float val[16]; int idx[16];
#pragma unroll
  for (int r = 0; r < 16; ++r) { val[r] = NEG_INF; idx[r] = 0; }

  for (int mt = 0; mt < MTILES; ++mt) {
    int m0 = mbase + mt * 128;
    __syncthreads();                             // prev tile's Ds reads done
#pragma unroll
    for (int k = 0; k < 8; ++k) {
      int chunk = tid + 256 * k;
      int c = chunk >> 5, cm = (chunk & 31) << 2;
      float4 v = *(const float4*)(xb + (size_t)c * NPTS + m0 + cm);
      *(float4*)(Bs + c * 128 + cm) = v;
    }
    __syncthreads();

    float acc[4][8];
#pragma unroll
    for (int i = 0; i < 4; ++i)
#pragma unroll
      for (int j = 0; j < 8; ++j) acc[i][j] = 0.f;

#pragma unroll 2
    for (int c = 0; c < CH; ++c) {               // same fp op order as R3/R4
      float4 a  = *(const float4*)(As + c * 64 + 4 * rg);
      float4 b0 = *(const float4*)(Bs + c * 128 + 4 * cg);
      float4 b1 = *(const float4*)(Bs + c * 128 + 64 + 4 * cg);
      float av[4] = {a.x, a.y, a.z, a.w};
      float bv[8] = {b0.x, b0.y, b0.z, b0.w, b1.x, b1.y, b1.z, b1.w};
#pragma unroll
      for (int i = 0; i < 4; ++i)
#pragma unroll
        for (int j = 0; j < 8; ++j) acc[i][j] = fmaf(av[i], bv[j], acc[i][j]);
    }

    float xmv[8];
#pragma unroll
    for (int j = 0; j < 4; ++j) xmv[j] = xxb[m0 + 4 * cg + j];
#pragma unroll
    for (int j = 0; j < 4; ++j) xmv[4 + j] = xxb[m0 + 64 + 4 * cg + j];

    __syncthreads();                             // Bs reads done; Ds may overwrite
#pragma unroll
    for (int i = 0; i < 4; ++i) {
      int R = 4 * rg + i;
      float4 d0, d1;
      d0.x = (2.f * acc[i][0] - xnr[i]) - xmv[0];
      d0.y = (2.f * acc[i][1] - xnr[i]) - xmv[1];
      d0.z = (2.f * acc[i][2] - xnr[i]) - xmv[2];
      d0.w = (2.f * acc[i][3] - xnr[i]) - xmv[3];
      d1.x = (2.f * acc[i][4] - xnr[i]) - xmv[4];
      d1.y = (2.f * acc[i][5] - xnr[i]) - xmv[5];
      d1.z = (2.f * acc[i][6] - xnr[i]) - xmv[6];
      d1.w = (2.f * acc[i][7] - xnr[i]) - xmv[7];
      *(float4*)(Ds + R * 128 + 4 * cg)      = d0;
      *(float4*)(Ds + R * 128 + 64 + 4 * cg) = d1;
    }
    __syncthreads();

    // selection: wave w scans rows 16w..16w+15; combined 2-group threshold test
#pragma unroll
    for (int r = 0; r < 16; ++r) {
      int R = 16 * w + r;
      const float* drow = Ds + R * 128;
      float d0 = drow[lane];
      float d1 = drow[64 + lane];
      float th = __shfl(val[r], KNN - 1);
      if (__ballot(fmaxf(d0, d1) > th)) {
        unsigned long long hit = __ballot(d0 > th);
        while (hit) {
          int j = __builtin_ctzll(hit);
          hit &= hit - 1;
          float cv = __shfl(d0, j);
          int cm = m0 + j;
          unsigned long long km = __ballot(val[r] >= cv);
          int cnt = __popcll(km);
          float sv = __shfl_up(val[r], 1);
          int si = __shfl_up(idx[r], 1);
          if (lane >= cnt) {
            val[r] = (lane == cnt) ? cv : sv;
            idx[r] = (lane == cnt) ? cm : si;
          }
        }
        float th2 = __shfl(val[r], KNN - 1);
        hit = __ballot(d1 > th2);
        while (hit) {
          int j = __builtin_ctzll(hit);
          hit &= hit - 1;
          float cv = __shfl(d1, j);
          int cm = m0 + 64 + j;
          unsigned long long km = __ballot(val[r] >= cv);
          int cnt = __popcll(km);
          float sv = __shfl_up(val[r], 1);
          int si = __shfl_up(idx[r], 1);
          if (lane >= cnt) {
            val[r] = (lane == cnt) ? cv : sv;
            idx[r] = (lane == cnt) ? cm : si;
          }
        }
      }
    }
  }

  // emit per-chunk top-20 (val,idx), sorted desc (ties: lowest m first)
#pragma unroll
  for (int r = 0; r < 16; ++r) {
    int n = n0 + 16 * w + r;
    size_t row = (size_t)mc * (BATCH * NPTS) + b * NPTS + n;
    if (lane < KNN) {
      pv[row * KNN + lane] = val[r];
      pi[row * KNN + lane] = idx[r];
    }
  }
}

// ---------------- K1b: merge two sorted 20-lists per row ----------------
__global__ void k_merge(const float* __restrict__ pv, const int* __restrict__ pi,
                        int* __restrict__ idxout) {
  int row = blockIdx.x * 256 + threadIdx.x;      // 0..32767
  const float* v0 = pv + (size_t)row * KNN;
  const int*   i0 = pi + (size_t)row * KNN;
  const float* v1 = pv + ((size_t)BATCH * NPTS + row) * KNN;
  const int*   i1 = pi + ((size_t)BATCH * NPTS + row) * KNN;
  int* op = idxout + (size_t)row * KNN;
  int p0 = 0, p1 = 0;
#pragma unroll
  for (int k = 0; k < KNN; ++k) {
    float f0 = v0[p0], f1 = v1[p1];
    // chunk0 indices are always smaller -> ties go to chunk0 (lax.top_k stable)
    if (f0 >= f1) { op[k] = i0[p0++]; } else { op[k] = i1[p1++]; }
  }
}

// ---------------- K3: gather + max + leaky, transpose to (B,O,N) ----------------
__global__ void k_out(const float* __restrict__ P, const float* __restrict__ Q,
                      const int* __restrict__ idx, float* __restrict__ out) {
  __shared__ float T[64 * 65];
  int tid = threadIdx.x;
  int nb = blockIdx.x, b = blockIdx.y;
  int n0 = nb * 64;
  int o = tid & 63, ng = tid >> 6;
  const float* Pb = P + (size_t)b * NPTS * 64;
  for (int p = 0; p < 16; ++p) {
    int nl = p * 4 + ng;
    int n = n0 + nl;
    const int* ip = idx + (size_t)(b * NPTS + n) * KNN;
    float mx = NEG_INF;
#pragma unroll
    for (int k = 0; k < KNN; ++k) {
      int id = ip[k];
      float v = Pb[(size_t)id * 64 + o];
      mx = fmaxf(mx, v);
    }
    float z = mx + Q[(size_t)(b * NPTS + n) * 64 + o];
    z = (z >= 0.f) ? z : NEG_SLOPE * z;
    T[o * 65 + nl] = z;
  }
  __syncthreads();
  float* ob = out + (size_t)b * 64 * NPTS + n0;
  int nl = tid & 63;
  for (int w = 0; w < 16; ++w) {
    int oo = w * 4 + ng;
    ob[(size_t)oo * NPTS + nl] = T[oo * 65 + nl];
  }
}

extern "C" void kernel_launch(void* const* d_in, const int* in_sizes, int n_in,
                              void* d_out, int out_size, void* d_ws, size_t ws_size,
                              hipStream_t stream) {
  const float* x     = (const float*)d_in[0];
  const float* W     = (const float*)d_in[1];
  const float* gamma = (const float*)d_in[2];
  const float* beta  = (const float*)d_in[3];
  const float* rmean = (const float*)d_in[4];
  const float* rvar  = (const float*)d_in[5];
  float* out = (float*)d_out;

  // ws layout (floats): xx 32768 | idx 655360 (int) | shared region:
  //   phase A: pv 1310720 f, pi 1310720 i   (k_knn -> k_merge)
  //   phase B: P 2097152 f,  Q 2097152 f    (k_pq  -> k_out)   [overlaps pv/pi]
  float* xx  = (float*)d_ws;
  int*   idx = (int*)(xx + 32768);
  float* reg = (float*)(idx + 655360);
  float* pv  = reg;
  int*   pi  = (int*)(reg + 1310720);
  float* P   = reg;
  float* Q   = reg + 2097152;

  k_xx<<<BATCH * NPTS / 256, 256, 0, stream>>>(x, xx);
  k_knn<<<dim3(NPTS / 64, 2, BATCH), 256, 0, stream>>>(x, xx, pv, pi);
  k_merge<<<BATCH * NPTS / 256, 256, 0, stream>>>(pv, pi, idx);
  k_pq<<<BATCH * NPTS / 16, 256, 0, stream>>>(x, W, gamma, beta, rmean, rvar, P, Q);
  k_out<<<dim3(NPTS / 64, BATCH), 256, 0, stream>>>(P, Q, idx, out);
}

// Round 6
// 776.243 us; speedup vs baseline: 1.1724x; 1.1698x over previous
//
#include <hip/hip_runtime.h>

#define NPTS 4096
#define CH 64
#define BATCH 8
#define KNN 20
#define NEG_SLOPE 0.2f
#define EPSV 1e-5f
#define NEG_INF (-3.4e38f)

// ---------------- K0: xx[b,n] = sum_c x[b,c,n]^2 ----------------
__global__ void k_xx(const float* __restrict__ x, float* __restrict__ xx) {
  int t = blockIdx.x * 256 + threadIdx.x;
  int b = t >> 12, n = t & (NPTS - 1);
  const float* xp = x + ((size_t)b * CH * NPTS) + n;
  float s = 0.f;
#pragma unroll
  for (int c = 0; c < CH; ++c) { float v = xp[(size_t)c * NPTS]; s = fmaf(v, v, s); }
  xx[t] = s;
}

// ---------------- K2: P'[t,o], Q'[t,o] ----------------
__global__ void k_pq(const float* __restrict__ x, const float* __restrict__ W,
                     const float* __restrict__ gamma, const float* __restrict__ beta,
                     const float* __restrict__ rmean, const float* __restrict__ rvar,
                     float* __restrict__ P, float* __restrict__ Q) {
  __shared__ float Ws1[CH * CH];
  __shared__ float Wsd[CH * CH];
  int tid = threadIdx.x;
  for (int i = tid; i < CH * CH; i += 256) {
    int o = i & 63, c = i >> 6;
    float s = gamma[o] * rsqrtf(rvar[o] + EPSV);
    float w1 = W[o * 128 + c], w2 = W[o * 128 + 64 + c];
    Ws1[c * 64 + o] = w1 * s;
    Wsd[c * 64 + o] = (w2 - w1) * s;
  }
  __syncthreads();
  int o = tid & 63, ng = tid >> 6;
  float s = gamma[o] * rsqrtf(rvar[o] + EPSV);
  float shift = beta[o] - rmean[o] * s;
  int base = blockIdx.x * 16;
  for (int rp = 0; rp < 4; ++rp) {
    int t = base + rp * 4 + ng;
    int b = t >> 12, n = t & (NPTS - 1);
    const float* xp = x + ((size_t)b * CH * NPTS) + n;
    float accp = 0.f, accq = 0.f;
#pragma unroll 8
    for (int c = 0; c < CH; ++c) {
      float xv = xp[(size_t)c * NPTS];
      accp = fmaf(xv, Ws1[c * 64 + o], accp);
      accq = fmaf(xv, Wsd[c * 64 + o], accq);
    }
    P[(size_t)t * 64 + o] = accp;
    Q[(size_t)t * 64 + o] = accq + shift;
  }
}

// ---------------- K1: distance-GEMM + wave top-20, full sweep, 2 barriers/tile
// Block 256 thr. Tile 64 rows x 128 cols, thread-tile 4x8 (cols 4+4 split).
// Grid 512 (row-partitioned ONLY: warm-up once per row). LDS 80KB:
//   As[c][64] 16KB | Bs[c][128] 32KB | Ds[64][128] 32KB (SEPARATE region)
// Wave w writes Ds rows 16w..16w+15 (rg=tid>>4 in [4w,4w+4)) and selects on
// exactly those rows -> no barrier between dist-write and selection.
// B-tile register double-buffer: next tile's global loads issue before GEMM.
__launch_bounds__(256, 2)
__global__ void k_knn(const float* __restrict__ x, const float* __restrict__ xx,
                      int* __restrict__ idxout) {
  __shared__ float S[20480];     // 80 KB
  float* As = S;                 // [c*64 + row]
  float* Bs = S + 4096;          // [c*128 + col]
  float* Ds = S + 12288;         // [r*128 + col]
  int tid = threadIdx.x;
  int lane = tid & 63, w = tid >> 6;
  int nb = blockIdx.x;           // 0..63
  int b  = blockIdx.y;           // 0..7
  int n0 = nb * 64;
  const float* xb = x + (size_t)b * CH * NPTS;
  const float* xxb = xx + b * NPTS;

  // stage A-tile [c][64 rows] once
#pragma unroll
  for (int k = 0; k < 4; ++k) {
    int chunk = tid + 256 * k;                   // 0..1023
    int c = chunk >> 4, rn = (chunk & 15) << 2;
    float4 v = *(const float4*)(xb + (size_t)c * NPTS + n0 + rn);
    *(float4*)(As + c * 64 + rn) = v;
  }

  int rg = tid >> 4, cg = tid & 15;              // rows 4rg..+3, cols {4cg,64+4cg}..+3

  float xnr[4];
#pragma unroll
  for (int i = 0; i < 4; ++i) xnr[i] = xxb[n0 + 4 * rg + i];

  // distributed top-20: lane l holds l-th best of row 16w+r
  float val[16]; int idx[16];
#pragma unroll
  for (int r = 0; r < 16; ++r) { val[r] = NEG_INF; idx[r] = 0; }

  // preload B-tile 0 into registers
  float4 Breg[8];
#pragma unroll
  for (int k = 0; k < 8; ++k) {
    int chunk = tid + 256 * k;
    int c = chunk >> 5, cm = (chunk & 31) << 2;
    Breg[k] = *(const float4*)(xb + (size_t)c * NPTS + cm);
  }

  for (int mt = 0; mt < NPTS / 128; ++mt) {
    int m0 = mt * 128;
    __syncthreads();                             // all waves' Bs reads (prev GEMM) done
#pragma unroll
    for (int k = 0; k < 8; ++k) {
      int chunk = tid + 256 * k;
      int c = chunk >> 5, cm = (chunk & 31) << 2;
      *(float4*)(Bs + c * 128 + cm) = Breg[k];
    }
    __syncthreads();                             // Bs ready
    if (mt + 1 < NPTS / 128) {                   // prefetch next tile (hidden by GEMM)
      int m1 = m0 + 128;
#pragma unroll
      for (int k = 0; k < 8; ++k) {
        int chunk = tid + 256 * k;
        int c = chunk >> 5, cm = (chunk & 31) << 2;
        Breg[k] = *(const float4*)(xb + (size_t)c * NPTS + m1 + cm);
      }
    }

    float acc[4][8];
#pragma unroll
    for (int i = 0; i < 4; ++i)
#pragma unroll
      for (int j = 0; j < 8; ++j) acc[i][j] = 0.f;

#pragma unroll 2
    for (int c = 0; c < CH; ++c) {               // same fp op order as R3/R4/R5
      float4 a  = *(const float4*)(As + c * 64 + 4 * rg);
      float4 b0 = *(const float4*)(Bs + c * 128 + 4 * cg);
      float4 b1 = *(const float4*)(Bs + c * 128 + 64 + 4 * cg);
      float av[4] = {a.x, a.y, a.z, a.w};
      float bv[8] = {b0.x, b0.y, b0.z, b0.w, b1.x, b1.y, b1.z, b1.w};
#pragma unroll
      for (int i = 0; i < 4; ++i)
#pragma unroll
        for (int j = 0; j < 8; ++j) acc[i][j] = fmaf(av[i], bv[j], acc[i][j]);
    }

    float xmv[8];
#pragma unroll
    for (int j = 0; j < 4; ++j) xmv[j] = xxb[m0 + 4 * cg + j];
#pragma unroll
    for (int j = 0; j < 4; ++j) xmv[4 + j] = xxb[m0 + 64 + 4 * cg + j];

    // distances -> Ds (own-wave rows; separate region -> NO barrier needed)
#pragma unroll
    for (int i = 0; i < 4; ++i) {
      int R = 4 * rg + i;
      float4 d0, d1;
      d0.x = (2.f * acc[i][0] - xnr[i]) - xmv[0];
      d0.y = (2.f * acc[i][1] - xnr[i]) - xmv[1];
      d0.z = (2.f * acc[i][2] - xnr[i]) - xmv[2];
      d0.w = (2.f * acc[i][3] - xnr[i]) - xmv[3];
      d1.x = (2.f * acc[i][4] - xnr[i]) - xmv[4];
      d1.y = (2.f * acc[i][5] - xnr[i]) - xmv[5];
      d1.z = (2.f * acc[i][6] - xnr[i]) - xmv[6];
      d1.w = (2.f * acc[i][7] - xnr[i]) - xmv[7];
      *(float4*)(Ds + R * 128 + 4 * cg)      = d0;
      *(float4*)(Ds + R * 128 + 64 + 4 * cg) = d1;
    }

    // selection: wave w scans rows 16w..16w+15 (its own Ds rows)
#pragma unroll
    for (int r = 0; r < 16; ++r) {
      int R = 16 * w + r;
      const float* drow = Ds + R * 128;
      float d0 = drow[lane];
      float d1 = drow[64 + lane];
      float th = __shfl(val[r], KNN - 1);
      if (__ballot(fmaxf(d0, d1) > th)) {
        unsigned long long hit = __ballot(d0 > th);
        while (hit) {
          int j = __builtin_ctzll(hit);
          hit &= hit - 1;
          float cv = __shfl(d0, j);
          int cm = m0 + j;
          unsigned long long km = __ballot(val[r] >= cv);
          int cnt = __popcll(km);
          float sv = __shfl_up(val[r], 1);
          int si = __shfl_up(idx[r], 1);
          if (lane >= cnt) {
            val[r] = (lane == cnt) ? cv : sv;
            idx[r] = (lane == cnt) ? cm : si;
          }
        }
        float th2 = __shfl(val[r], KNN - 1);
        hit = __ballot(d1 > th2);
        while (hit) {
          int j = __builtin_ctzll(hit);
          hit &= hit - 1;
          float cv = __shfl(d1, j);
          int cm = m0 + 64 + j;
          unsigned long long km = __ballot(val[r] >= cv);
          int cnt = __popcll(km);
          float sv = __shfl_up(val[r], 1);
          int si = __shfl_up(idx[r], 1);
          if (lane >= cnt) {
            val[r] = (lane == cnt) ? cv : sv;
            idx[r] = (lane == cnt) ? cm : si;
          }
        }
      }
    }
  }

  // emit top-20 indices (lane l = l-th best)
#pragma unroll
  for (int r = 0; r < 16; ++r) {
    int n = n0 + 16 * w + r;
    if (lane < KNN) idxout[(size_t)(b * NPTS + n) * KNN + lane] = idx[r];
  }
}

// ---------------- K3: gather + max + leaky, transpose to (B,O,N) ----------------
__global__ void k_out(const float* __restrict__ P, const float* __restrict__ Q,
                      const int* __restrict__ idx, float* __restrict__ out) {
  __shared__ float T[64 * 65];
  int tid = threadIdx.x;
  int nb = blockIdx.x, b = blockIdx.y;
  int n0 = nb * 64;
  int o = tid & 63, ng = tid >> 6;
  const float* Pb = P + (size_t)b * NPTS * 64;
  for (int p = 0; p < 16; ++p) {
    int nl = p * 4 + ng;
    int n = n0 + nl;
    const int* ip = idx + (size_t)(b * NPTS + n) * KNN;
    float mx = NEG_INF;
#pragma unroll
    for (int k = 0; k < KNN; ++k) {
      int id = ip[k];
      float v = Pb[(size_t)id * 64 + o];
      mx = fmaxf(mx, v);
    }
    float z = mx + Q[(size_t)(b * NPTS + n) * 64 + o];
    z = (z >= 0.f) ? z : NEG_SLOPE * z;
    T[o * 65 + nl] = z;
  }
  __syncthreads();
  float* ob = out + (size_t)b * 64 * NPTS + n0;
  int nl = tid & 63;
  for (int w = 0; w < 16; ++w) {
    int oo = w * 4 + ng;
    ob[(size_t)oo * NPTS + nl] = T[oo * 65 + nl];
  }
}

extern "C" void kernel_launch(void* const* d_in, const int* in_sizes, int n_in,
                              void* d_out, int out_size, void* d_ws, size_t ws_size,
                              hipStream_t stream) {
  const float* x     = (const float*)d_in[0];
  const float* W     = (const float*)d_in[1];
  const float* gamma = (const float*)d_in[2];
  const float* beta  = (const float*)d_in[3];
  const float* rmean = (const float*)d_in[4];
  const float* rvar  = (const float*)d_in[5];
  float* out = (float*)d_out;

  float* xx  = (float*)d_ws;                     // 32768 f
  int*   idx = (int*)(xx + 32768);               // 655360 i
  float* P   = (float*)(idx + 655360);           // 2097152 f
  float* Q   = P + 2097152;                      // 2097152 f

  k_xx<<<BATCH * NPTS / 256, 256, 0, stream>>>(x, xx);
  k_knn<<<dim3(NPTS / 64, BATCH), 256, 0, stream>>>(x, xx, idx);
  k_pq<<<BATCH * NPTS / 16, 256, 0, stream>>>(x, W, gamma, beta, rmean, rvar, P, Q);
  k_out<<<dim3(NPTS / 64, BATCH), 256, 0, stream>>>(P, Q, idx, out);
}

// Round 7
// 723.994 us; speedup vs baseline: 1.2570x; 1.0722x over previous
//
#include <hip/hip_runtime.h>

#define NPTS 4096
#define CH 64
#define BATCH 8
#define KNN 20
#define NEG_SLOPE 0.2f
#define EPSV 1e-5f
#define NEG_INF (-3.4e38f)

#define AS1(p) ((const __attribute__((address_space(1))) void*)(p))
#define AS3(p) ((__attribute__((address_space(3))) void*)(p))

// ---------------- K0: xx[b,n] = sum_c x[b,c,n]^2 ----------------
__global__ void k_xx(const float* __restrict__ x, float* __restrict__ xx) {
  int t = blockIdx.x * 256 + threadIdx.x;
  int b = t >> 12, n = t & (NPTS - 1);
  const float* xp = x + ((size_t)b * CH * NPTS) + n;
  float s = 0.f;
#pragma unroll
  for (int c = 0; c < CH; ++c) { float v = xp[(size_t)c * NPTS]; s = fmaf(v, v, s); }
  xx[t] = s;
}

// ---------------- K2: P'[t,o], Q'[t,o] ----------------
__global__ void k_pq(const float* __restrict__ x, const float* __restrict__ W,
                     const float* __restrict__ gamma, const float* __restrict__ beta,
                     const float* __restrict__ rmean, const float* __restrict__ rvar,
                     float* __restrict__ P, float* __restrict__ Q) {
  __shared__ float Ws1[CH * CH];
  __shared__ float Wsd[CH * CH];
  int tid = threadIdx.x;
  for (int i = tid; i < CH * CH; i += 256) {
    int o = i & 63, c = i >> 6;
    float s = gamma[o] * rsqrtf(rvar[o] + EPSV);
    float w1 = W[o * 128 + c], w2 = W[o * 128 + 64 + c];
    Ws1[c * 64 + o] = w1 * s;
    Wsd[c * 64 + o] = (w2 - w1) * s;
  }
  __syncthreads();
  int o = tid & 63, ng = tid >> 6;
  float s = gamma[o] * rsqrtf(rvar[o] + EPSV);
  float shift = beta[o] - rmean[o] * s;
  int base = blockIdx.x * 16;
  for (int rp = 0; rp < 4; ++rp) {
    int t = base + rp * 4 + ng;
    int b = t >> 12, n = t & (NPTS - 1);
    const float* xp = x + ((size_t)b * CH * NPTS) + n;
    float accp = 0.f, accq = 0.f;
#pragma unroll 8
    for (int c = 0; c < CH; ++c) {
      float xv = xp[(size_t)c * NPTS];
      accp = fmaf(xv, Ws1[c * 64 + o], accp);
      accq = fmaf(xv, Wsd[c * 64 + o], accq);
    }
    P[(size_t)t * 64 + o] = accp;
    Q[(size_t)t * 64 + o] = accq + shift;
  }
}

// ---------------- K1: distance-GEMM + wave top-20, async B staging ----------
// Block 256 thr. Tile 64 rows x 128 cols, thread-tile 4x8 (cols 4+4 split).
// Grid 512 (row-partitioned: top-20 warm-up once per row). LDS 80KB:
//   As[c][64] 16KB | Bs[c][128] 32KB | Ds[64][128] 32KB
// B staged via __builtin_amdgcn_global_load_lds width=16 (async DMA, no VGPRs,
// no spill): issued right after the GEMM-done barrier, in flight during
// distance-write + selection; loop-top __syncthreads() drains vmcnt.
// Wave w writes Ds rows 16w..16w+15 and selects on exactly those rows ->
// no barrier between distance write and selection (2 barriers/tile total).
__launch_bounds__(256, 2)
__global__ void k_knn(const float* __restrict__ x, const float* __restrict__ xx,
                      int* __restrict__ idxout) {
  __shared__ float S[20480];     // 80 KB
  float* As = S;                 // [c*64 + row]
  float* Bs = S + 4096;          // [c*128 + col]
  float* Ds = S + 12288;         // [r*128 + col]
  int tid = threadIdx.x;
  int lane = tid & 63, w = tid >> 6;
  int nb = blockIdx.x;           // 0..63
  int b  = blockIdx.y;           // 0..7
  int n0 = nb * 64;
  const float* xb = x + (size_t)b * CH * NPTS;
  const float* xxb = xx + b * NPTS;

  // stage A-tile [c][64 rows] once (normal LDS stores; drained at loop-top barrier)
#pragma unroll
  for (int k = 0; k < 4; ++k) {
    int chunk = tid + 256 * k;                   // 0..1023
    int c = chunk >> 4, rn = (chunk & 15) << 2;
    float4 v = *(const float4*)(xb + (size_t)c * NPTS + n0 + rn);
    *(float4*)(As + c * 64 + rn) = v;
  }

  // async B staging: wave w handles chunks q=8w..8w+7; chunk q = Bs floats
  // [256q, 256q+256) = rows c0=2q,2q+1 of [c][128]; lane l deposits 16B at
  // base+16l -> (c = 2q + (l>>5), col = (l&31)*4). Global addr per lane matches.
  int bl_c = lane >> 5, bl_f = (lane & 31) << 2; // lane's (c-offset, col) in chunk
#define ISSUE_B_TILE(M0)                                                        \
  {                                                                             \
    _Pragma("unroll")                                                           \
    for (int k = 0; k < 8; ++k) {                                               \
      int q = 8 * w + k;                                                        \
      const float* gp = xb + (size_t)(2 * q + bl_c) * NPTS + (M0) + bl_f;       \
      __builtin_amdgcn_global_load_lds(AS1(gp), AS3(Bs + 256 * q), 16, 0, 0);   \
    }                                                                           \
  }

  ISSUE_B_TILE(0)                                // tile 0 in flight

  int rg = tid >> 4, cg = tid & 15;              // rows 4rg..+3, cols {4cg,64+4cg}..+3

  float xnr[4];
#pragma unroll
  for (int i = 0; i < 4; ++i) xnr[i] = xxb[n0 + 4 * rg + i];

  // distributed top-20: lane l holds l-th best of row 16w+r
  float val[16]; int idx[16];
#pragma unroll
  for (int r = 0; r < 16; ++r) { val[r] = NEG_INF; idx[r] = 0; }

  for (int mt = 0; mt < NPTS / 128; ++mt) {
    int m0 = mt * 128;
    __syncthreads();                             // drains vmcnt: Bs(mt) arrived, all ready

    float acc[4][8];
#pragma unroll
    for (int i = 0; i < 4; ++i)
#pragma unroll
      for (int j = 0; j < 8; ++j) acc[i][j] = 0.f;

#pragma unroll 2
    for (int c = 0; c < CH; ++c) {               // same fp op order as R3..R6
      float4 a  = *(const float4*)(As + c * 64 + 4 * rg);
      float4 b0 = *(const float4*)(Bs + c * 128 + 4 * cg);
      float4 b1 = *(const float4*)(Bs + c * 128 + 64 + 4 * cg);
      float av[4] = {a.x, a.y, a.z, a.w};
      float bv[8] = {b0.x, b0.y, b0.z, b0.w, b1.x, b1.y, b1.z, b1.w};
#pragma unroll
      for (int i = 0; i < 4; ++i)
#pragma unroll
        for (int j = 0; j < 8; ++j) acc[i][j] = fmaf(av[i], bv[j], acc[i][j]);
    }
    __syncthreads();                             // all waves' Bs(mt) reads done

    if (mt + 1 < NPTS / 128) ISSUE_B_TILE(m0 + 128)  // async, overlaps selection

    float xmv[8];
#pragma unroll
    for (int j = 0; j < 4; ++j) xmv[j] = xxb[m0 + 4 * cg + j];
#pragma unroll
    for (int j = 0; j < 4; ++j) xmv[4 + j] = xxb[m0 + 64 + 4 * cg + j];

    // distances -> Ds (own-wave rows; separate region -> no barrier)
#pragma unroll
    for (int i = 0; i < 4; ++i) {
      int R = 4 * rg + i;
      float4 d0, d1;
      d0.x = (2.f * acc[i][0] - xnr[i]) - xmv[0];
      d0.y = (2.f * acc[i][1] - xnr[i]) - xmv[1];
      d0.z = (2.f * acc[i][2] - xnr[i]) - xmv[2];
      d0.w = (2.f * acc[i][3] - xnr[i]) - xmv[3];
      d1.x = (2.f * acc[i][4] - xnr[i]) - xmv[4];
      d1.y = (2.f * acc[i][5] - xnr[i]) - xmv[5];
      d1.z = (2.f * acc[i][6] - xnr[i]) - xmv[6];
      d1.w = (2.f * acc[i][7] - xnr[i]) - xmv[7];
      *(float4*)(Ds + R * 128 + 4 * cg)      = d0;
      *(float4*)(Ds + R * 128 + 64 + 4 * cg) = d1;
    }

    // selection: wave w scans rows 16w..16w+15 (its own Ds rows)
#pragma unroll
    for (int r = 0; r < 16; ++r) {
      int R = 16 * w + r;
      const float* drow = Ds + R * 128;
      float d0 = drow[lane];
      float d1 = drow[64 + lane];
      float th = __shfl(val[r], KNN - 1);
      if (__ballot(fmaxf(d0, d1) > th)) {
        unsigned long long hit = __ballot(d0 > th);
        while (hit) {
          int j = __builtin_ctzll(hit);
          hit &= hit - 1;
          float cv = __shfl(d0, j);
          int cm = m0 + j;
          unsigned long long km = __ballot(val[r] >= cv);
          int cnt = __popcll(km);
          float sv = __shfl_up(val[r], 1);
          int si = __shfl_up(idx[r], 1);
          if (lane >= cnt) {
            val[r] = (lane == cnt) ? cv : sv;
            idx[r] = (lane == cnt) ? cm : si;
          }
        }
        float th2 = __shfl(val[r], KNN - 1);
        hit = __ballot(d1 > th2);
        while (hit) {
          int j = __builtin_ctzll(hit);
          hit &= hit - 1;
          float cv = __shfl(d1, j);
          int cm = m0 + 64 + j;
          unsigned long long km = __ballot(val[r] >= cv);
          int cnt = __popcll(km);
          float sv = __shfl_up(val[r], 1);
          int si = __shfl_up(idx[r], 1);
          if (lane >= cnt) {
            val[r] = (lane == cnt) ? cv : sv;
            idx[r] = (lane == cnt) ? cm : si;
          }
        }
      }
    }
  }

  // emit top-20 indices (lane l = l-th best)
#pragma unroll
  for (int r = 0; r < 16; ++r) {
    int n = n0 + 16 * w + r;
    if (lane < KNN) idxout[(size_t)(b * NPTS + n) * KNN + lane] = idx[r];
  }
#undef ISSUE_B_TILE
}

// ---------------- K3: gather + max + leaky, transpose to (B,O,N) ----------------
__global__ void k_out(const float* __restrict__ P, const float* __restrict__ Q,
                      const int* __restrict__ idx, float* __restrict__ out) {
  __shared__ float T[64 * 65];
  int tid = threadIdx.x;
  int nb = blockIdx.x, b = blockIdx.y;
  int n0 = nb * 64;
  int o = tid & 63, ng = tid >> 6;
  const float* Pb = P + (size_t)b * NPTS * 64;
  for (int p = 0; p < 16; ++p) {
    int nl = p * 4 + ng;
    int n = n0 + nl;
    const int* ip = idx + (size_t)(b * NPTS + n) * KNN;
    float mx = NEG_INF;
#pragma unroll
    for (int k = 0; k < KNN; ++k) {
      int id = ip[k];
      float v = Pb[(size_t)id * 64 + o];
      mx = fmaxf(mx, v);
    }
    float z = mx + Q[(size_t)(b * NPTS + n) * 64 + o];
    z = (z >= 0.f) ? z : NEG_SLOPE * z;
    T[o * 65 + nl] = z;
  }
  __syncthreads();
  float* ob = out + (size_t)b * 64 * NPTS + n0;
  int nl = tid & 63;
  for (int w = 0; w < 16; ++w) {
    int oo = w * 4 + ng;
    ob[(size_t)oo * NPTS + nl] = T[oo * 65 + nl];
  }
}

extern "C" void kernel_launch(void* const* d_in, const int* in_sizes, int n_in,
                              void* d_out, int out_size, void* d_ws, size_t ws_size,
                              hipStream_t stream) {
  const float* x     = (const float*)d_in[0];
  const float* W     = (const float*)d_in[1];
  const float* gamma = (const float*)d_in[2];
  const float* beta  = (const float*)d_in[3];
  const float* rmean = (const float*)d_in[4];
  const float* rvar  = (const float*)d_in[5];
  float* out = (float*)d_out;

  float* xx  = (float*)d_ws;                     // 32768 f
  int*   idx = (int*)(xx + 32768);               // 655360 i
  float* P   = (float*)(idx + 655360);           // 2097152 f
  float* Q   = P + 2097152;                      // 2097152 f

  k_xx<<<BATCH * NPTS / 256, 256, 0, stream>>>(x, xx);
  k_knn<<<dim3(NPTS / 64, BATCH), 256, 0, stream>>>(x, xx, idx);
  k_pq<<<BATCH * NPTS / 16, 256, 0, stream>>>(x, W, gamma, beta, rmean, rvar, P, Q);
  k_out<<<dim3(NPTS / 64, BATCH), 256, 0, stream>>>(P, Q, idx, out);
}